// Round 4
// baseline (236.230 us; speedup 1.0000x reference)
//
#include <hip/hip_runtime.h>

// MpMaxPoolingMatch: out[b,t,m] = tanh( max_s sum_d lt[b,t,d]*km[m,d]*rt[b,s,d] )
// B=32, T=256, D=512, MP=20.
// R14: phase-pipelined m-loop. R12/R13 post-mortem: dur/MfmaUtil/VALUBusy
// invariant across 3 different B paths -> K-loop never B/VALU-bound. Occupancy
// pinned at 2 waves/SIMD by the unified-regfile allocation quantum (144 regs ->
// (128,256] bucket, m69) -> more waves impossible; registers up to ~250 are FREE.
// So: hide the exposed serial phases (A-stage ~1.5k cy, epilogue) under MFMA via
// cross-phase ILP in the SAME wave:
//  * each block does G=5 m-values; grid = 32b x 4t0 x 4mg = 512 = exactly
//    2 blocks/CU resident for the whole kernel (no ramp, no tail).
//  * while K-loop(m_i) runs on the matrix pipe, the same waves stage
//    A(m_{i+1}) (lt load -> *km -> fp8 -> Ash[dbuf]) on VALU/LS pipes (m114
//    co-schedule). Row loads issue 2 steps before their convert (~280cy cover).
//  * B-ring wraps across phases (next phase's steps 0..2 issue at steps 13..15);
//    B is IDENTICAL for all m of a block (same b) -> rtf slice L2-hot.
//  * per XCD only 16 distinct lt slices (2MB) are live -> lt fully L2-resident
//    (was 8.4MB thrashing to LLC with 1-m blocks).
//  * maxbuf phase-parity dbuf -> ONE barrier per phase.
// LDS = 2x34.8K (Ash dbuf) + 2K (maxbuf dbuf) = 71.7KB -> 2 blocks/CU (LDS and
// regs agree). launch_bounds(256,2) relaxes the reg cap to 256.
// MFMA byte order/scales (e8m0=127) bitwise-identical to R10-R13.

constexpr int TT = 256;   // T
constexpr int DD = 512;   // D
constexpr int NM = 20;    // MP
constexpr int NB = 32;    // B
constexpr int BM = 64;    // t-tile
constexpr int GM = 5;     // m-values per block

typedef float f32x4 __attribute__((ext_vector_type(4)));
typedef int   i32x8 __attribute__((ext_vector_type(8)));

__device__ __forceinline__ unsigned pack_bf16(float lo, float hi) {
    unsigned ulo = __builtin_bit_cast(unsigned, lo);
    unsigned uhi = __builtin_bit_cast(unsigned, hi);
    return (ulo >> 16) | (uhi & 0xFFFF0000u);
}

// 4 fp32 -> 4 fp8 (e4m3, packed dword)
__device__ __forceinline__ unsigned pk4_fp8(float a, float b, float c, float d) {
    unsigned r = __builtin_amdgcn_cvt_pk_fp8_f32(a, b, 0, false);
    return __builtin_amdgcn_cvt_pk_fp8_f32(c, d, r, true);
}

// ---------------- Phase 1: rt fp32 -> fp8, 32B-contiguous lane tiles, XCD-aligned ----
// rtf layout: 32B element e = (b*4096 + (kk*16+g)*64 + lane):
//   holds rt[b][s = g*16 + (lane&15)][d = kk*128 + (lane>>4)*32 .. +32] as fp8.
__global__ __launch_bounds__(256)
void cast_rt(const float* __restrict__ rt, unsigned char* __restrict__ rtf)
{
    const int bid = (int)blockIdx.x;       // 0..511
    const int c8  = bid & 7;               // this block's XCD (flat%8)
    const int i   = bid >> 3;              // 0..63
    const int b   = c8 + 8 * (i & 3);      // b%8 == c8 == consumer XCD
    const int sub = i >> 2;                // 0..15
    const int tid = threadIdx.x;
    const int lane = tid & 63;
    const int u6  = sub * 4 + (tid >> 6);  // 0..63 == kk*16 + g
    const int s   = (u6 & 15) * 16 + (lane & 15);
    const int d0  = (u6 >> 4) * 128 + (lane >> 4) * 32;

    const float* p = rt + ((size_t)b * TT + s) * DD + d0;
    float4 x0 = *(const float4*)p;
    float4 x1 = *(const float4*)(p + 4);
    float4 x2 = *(const float4*)(p + 8);
    float4 x3 = *(const float4*)(p + 12);
    float4 x4 = *(const float4*)(p + 16);
    float4 x5 = *(const float4*)(p + 20);
    float4 x6 = *(const float4*)(p + 24);
    float4 x7 = *(const float4*)(p + 28);
    uint4 w0, w1;
    w0.x = pk4_fp8(x0.x, x0.y, x0.z, x0.w);
    w0.y = pk4_fp8(x1.x, x1.y, x1.z, x1.w);
    w0.z = pk4_fp8(x2.x, x2.y, x2.z, x2.w);
    w0.w = pk4_fp8(x3.x, x3.y, x3.z, x3.w);
    w1.x = pk4_fp8(x4.x, x4.y, x4.z, x4.w);
    w1.y = pk4_fp8(x5.x, x5.y, x5.z, x5.w);
    w1.z = pk4_fp8(x6.x, x6.y, x6.z, x6.w);
    w1.w = pk4_fp8(x7.x, x7.y, x7.z, x7.w);
    unsigned char* dst = rtf + ((size_t)b * 4096 + (size_t)u6 * 64 + lane) * 32;
    *(uint4*)dst        = w0;
    *(uint4*)(dst + 16) = w1;
}

// ---------------- Main: 64t x 256s x 5m, MX fp8 K=128, phase-pipelined ----------------
__global__ __launch_bounds__(256, 2)
void mp_match_mx(const float* __restrict__ lt, const unsigned char* __restrict__ rtf,
                 const float* __restrict__ km, float* __restrict__ out)
{
    __shared__ __attribute__((aligned(32))) uint4 Ash[2][BM * 34];   // 69.6 KB dbuf
    __shared__ __attribute__((aligned(16))) float maxbuf[2][4][BM];  // 2 KB dbuf

    // XCD swizzle: flat%8 == XCD; b%8 == XCD.
    const int f  = blockIdx.x;           // 0..511
    const int c8 = f & 7;
    const int i  = f >> 3;               // 0..63
    const int b  = c8 + 8 * (i & 3);     // 0..31
    const int r2 = i >> 2;               // 0..15
    const int mg = r2 & 3;               // m-group: m = mg*5 + mi
    const int t0 = (r2 >> 2) * BM;       // 0,64,128,192

    const int tid  = threadIdx.x;
    const int w    = tid >> 6;           // wave id = s-quarter owner
    const int lane = tid & 63;
    const int l15  = lane & 15;
    const int l4   = lane >> 4;

    const float* ltB = lt + ((size_t)b * TT + t0) * DD;
    // step u: one 32B contiguous load per wave-lane; identical for all phases.
    const unsigned char* rtB0 = rtf + (size_t)b * 131072 + (size_t)(w * 64 + lane) * 32;

    i32x8 ring[4];
    auto loadB = [&](int u) {
        ring[u & 3] = *(const i32x8*)(rtB0 + u * 8192);
    };

    // 3-deep prologue: in flight under the whole first A conversion.
    loadB(0); loadB(1); loadB(2);

    // ---- Prologue A staging (phase 0): thread -> chunk-col cc, rows r0..r0+8.
    const int cc = tid & 31, r0 = (tid >> 5) * 8;
    {
        const float* kmp = km + (size_t)(mg * GM) * DD + cc * 16;
        const float4 kA = *(const float4*)(kmp);
        const float4 kB = *(const float4*)(kmp + 4);
        const float4 kC = *(const float4*)(kmp + 8);
        const float4 kD = *(const float4*)(kmp + 12);
#pragma unroll
        for (int r = 0; r < 8; ++r) {
            const float* src = ltB + (size_t)(r0 + r) * DD + cc * 16;
            float4 x0 = *(const float4*)src;
            float4 x1 = *(const float4*)(src + 4);
            float4 x2 = *(const float4*)(src + 8);
            float4 x3 = *(const float4*)(src + 12);
            uint4 o;
            o.x = pk4_fp8(x0.x * kA.x, x0.y * kA.y, x0.z * kA.z, x0.w * kA.w);
            o.y = pk4_fp8(x1.x * kB.x, x1.y * kB.y, x1.z * kB.z, x1.w * kB.w);
            o.z = pk4_fp8(x2.x * kC.x, x2.y * kC.y, x2.z * kC.z, x2.w * kC.w);
            o.w = pk4_fp8(x3.x * kD.x, x3.y * kD.y, x3.z * kD.z, x3.w * kD.w);
            Ash[0][(r0 + r) * 34 + cc] = o;
        }
    }
    __syncthreads();

    for (int mi = 0; mi < GM; ++mi) {
        const uint4* Acur = &Ash[mi & 1][0];
        uint4*       Anx  = &Ash[(mi + 1) & 1][0];
        const bool   more = (mi + 1 < GM);
        const float* kmn  = km + (size_t)(mg * GM + mi + 1) * DD + cc * 16;  // used iff more

        f32x4 acc[4][4] = {};   // [ii][q]: t = t0+ii*16+..., s = q*64 + w*16 + ...
        i32x8 av[4];
        float4 kAn{}, kBn{}, kCn{}, kDn{};
        float4 xr[2][4];

#pragma unroll
        for (int u = 0; u < 16; ++u) {
            const int kk = u >> 2, q = u & 3;
            // B-ring: wrap next phase's first 3 steps into this phase's tail.
            const int un = u + 3;
            if (un < 16) loadB(un);
            else if (more) loadB(un - 16);

            if (more) {
                if (u == 0) {
                    kAn = *(const float4*)(kmn);
                    kBn = *(const float4*)(kmn + 4);
                    kCn = *(const float4*)(kmn + 8);
                    kDn = *(const float4*)(kmn + 12);
                }
                // convert row u-2 (loaded 2 steps ago; ~280cy L2 cover), THEN
                // load row u into the same slot (WAR keeps order).
                if (u >= 2 && u < 10) {
                    const int r = u - 2;
                    uint4 o;
                    o.x = pk4_fp8(xr[r & 1][0].x * kAn.x, xr[r & 1][0].y * kAn.y,
                                  xr[r & 1][0].z * kAn.z, xr[r & 1][0].w * kAn.w);
                    o.y = pk4_fp8(xr[r & 1][1].x * kBn.x, xr[r & 1][1].y * kBn.y,
                                  xr[r & 1][1].z * kBn.z, xr[r & 1][1].w * kBn.w);
                    o.z = pk4_fp8(xr[r & 1][2].x * kCn.x, xr[r & 1][2].y * kCn.y,
                                  xr[r & 1][2].z * kCn.z, xr[r & 1][2].w * kCn.w);
                    o.w = pk4_fp8(xr[r & 1][3].x * kDn.x, xr[r & 1][3].y * kDn.y,
                                  xr[r & 1][3].z * kDn.z, xr[r & 1][3].w * kDn.w);
                    Anx[(r0 + r) * 34 + cc] = o;
                }
                if (u < 8) {
                    const float* src = ltB + (size_t)(r0 + u) * DD + cc * 16;
                    xr[u & 1][0] = *(const float4*)src;
                    xr[u & 1][1] = *(const float4*)(src + 4);
                    xr[u & 1][2] = *(const float4*)(src + 8);
                    xr[u & 1][3] = *(const float4*)(src + 12);
                }
            }

            if (q == 0) {
                // A frags for this kk: row = ii*16 + l15, 32B at chunk kk*8 + l4*2.
#pragma unroll
                for (int ii = 0; ii < 4; ++ii)
                    av[ii] = *(const i32x8*)&Acur[(ii * 16 + l15) * 34 + kk * 8 + l4 * 2];
            }
            const i32x8 bv = ring[u & 3];
#pragma unroll
            for (int ii = 0; ii < 4; ++ii)
                acc[ii][q] = __builtin_amdgcn_mfma_scale_f32_16x16x128_f8f6f4(
                    av[ii], bv, acc[ii][q], 0, 0, 0, 127, 0, 127);  // fmt=fp8, scales=1.0
        }

        // ---- Epilogue(m): max over s. C layout: col(s)=lane&15, row(t)=(lane>>4)*4+reg.
        const int m = mg * GM + mi;
#pragma unroll
        for (int ii = 0; ii < 4; ++ii) {
            f32x4 v = acc[ii][0];
#pragma unroll
            for (int q = 1; q < 4; ++q) {
                v.x = fmaxf(v.x, acc[ii][q].x);
                v.y = fmaxf(v.y, acc[ii][q].y);
                v.z = fmaxf(v.z, acc[ii][q].z);
                v.w = fmaxf(v.w, acc[ii][q].w);
            }
#pragma unroll
            for (int off = 1; off < 16; off <<= 1) {
                v.x = fmaxf(v.x, __shfl_xor(v.x, off, 64));
                v.y = fmaxf(v.y, __shfl_xor(v.y, off, 64));
                v.z = fmaxf(v.z, __shfl_xor(v.z, off, 64));
                v.w = fmaxf(v.w, __shfl_xor(v.w, off, 64));
            }
            if (l15 == 0)
                *(f32x4*)&maxbuf[mi & 1][w][ii * 16 + l4 * 4] = v;
        }
        __syncthreads();   // maxbuf(mi) ready; Ash[(mi+1)&1] writes drained; Acur reads done
        if (tid < BM) {
            float v = fmaxf(fmaxf(maxbuf[mi & 1][0][tid], maxbuf[mi & 1][1][tid]),
                            fmaxf(maxbuf[mi & 1][2][tid], maxbuf[mi & 1][3][tid]));
            out[((size_t)b * TT + t0 + tid) * NM + m] = tanhf(v);
        }
        // maxbuf WAR across phases handled by parity (mi&1); next reuse of this
        // parity is separated by phase mi+1's full barrier.
    }
}

// ---------------- R1 fallback (no workspace): bf16 MFMA, fp32 register staging ----------------
typedef short bf16x8 __attribute__((ext_vector_type(8)));

__global__ __launch_bounds__(256, 2)
void mp_match_kernel(const float* __restrict__ lt, const float* __restrict__ rt,
                     const float* __restrict__ km, float* __restrict__ out)
{
    __shared__ __attribute__((aligned(16))) unsigned short Ash[2][4][128][8];
    __shared__ __attribute__((aligned(16))) unsigned short Bsh2[2][4][256][8];
    __shared__ __attribute__((aligned(16))) float maxbuf[2][128];

    const int ttile = blockIdx.x, m = blockIdx.y, b = blockIdx.z;
    const int t0 = ttile * 128;
    const int tid = threadIdx.x, wave = tid >> 6, lane = tid & 63;
    const int l15 = lane & 15, l4 = lane >> 4;
    const int wt = (wave & 1) * 64, wsi = wave >> 1;

    const float* ltp = lt + ((size_t)b * TT + t0) * DD;
    const float* rtp = rt + (size_t)b * TT * DD;
    const float* kmp = km + (size_t)m * DD;
    const int a_t = tid >> 1, a_h = tid & 1;

    f32x4 acc[4][8] = {};

    auto stage = [&](int kk, int buf) {
        const int d0 = kk * 32;
        const float* ap = ltp + (size_t)a_t * DD + d0 + a_h * 16;
        const float* kp = kmp + d0 + a_h * 16;
#pragma unroll
        for (int q = 0; q < 2; ++q) {
            float4 x0 = *(const float4*)(ap + q * 8);
            float4 x1 = *(const float4*)(ap + q * 8 + 4);
            float4 k0 = *(const float4*)(kp + q * 8);
            float4 k1 = *(const float4*)(kp + q * 8 + 4);
            uint4 wv;
            wv.x = pack_bf16(x0.x * k0.x, x0.y * k0.y);
            wv.y = pack_bf16(x0.z * k0.z, x0.w * k0.w);
            wv.z = pack_bf16(x1.x * k1.x, x1.y * k1.y);
            wv.w = pack_bf16(x1.z * k1.z, x1.w * k1.w);
            *(uint4*)&Ash[buf][a_h * 2 + q][a_t][0] = wv;
        }
        const float* bp = rtp + (size_t)tid * DD + d0;
#pragma unroll
        for (int p = 0; p < 4; ++p) {
            float4 y0 = *(const float4*)(bp + p * 8);
            float4 y1 = *(const float4*)(bp + p * 8 + 4);
            uint4 wv;
            wv.x = pack_bf16(y0.x, y0.y);
            wv.y = pack_bf16(y0.z, y0.w);
            wv.z = pack_bf16(y1.x, y1.y);
            wv.w = pack_bf16(y1.z, y1.w);
            *(uint4*)&Bsh2[buf][p][tid][0] = wv;
        }
    };

    stage(0, 0);
    for (int kk = 0; kk < 16; ++kk) {
        const int buf = kk & 1;
        __syncthreads();
        bf16x8 af[4], bfv[8];
#pragma unroll
        for (int i2 = 0; i2 < 4; ++i2)
            af[i2] = *(const bf16x8*)&Ash[buf][l4][wt + i2 * 16 + l15][0];
#pragma unroll
        for (int j2 = 0; j2 < 8; ++j2)
            bfv[j2] = *(const bf16x8*)&Bsh2[buf][l4][wsi * 128 + j2 * 16 + l15][0];
        if (kk + 1 < 16) stage(kk + 1, buf ^ 1);
#pragma unroll
        for (int i2 = 0; i2 < 4; ++i2)
#pragma unroll
            for (int j2 = 0; j2 < 8; ++j2)
                acc[i2][j2] = __builtin_amdgcn_mfma_f32_16x16x32_bf16(af[i2], bfv[j2], acc[i2][j2], 0, 0, 0);
    }
#pragma unroll
    for (int i2 = 0; i2 < 4; ++i2) {
        f32x4 v = acc[i2][0];
#pragma unroll
        for (int j2 = 1; j2 < 8; ++j2) {
            v.x = fmaxf(v.x, acc[i2][j2].x); v.y = fmaxf(v.y, acc[i2][j2].y);
            v.z = fmaxf(v.z, acc[i2][j2].z); v.w = fmaxf(v.w, acc[i2][j2].w);
        }
#pragma unroll
        for (int off = 1; off < 16; off <<= 1) {
            v.x = fmaxf(v.x, __shfl_xor(v.x, off, 64));
            v.y = fmaxf(v.y, __shfl_xor(v.y, off, 64));
            v.z = fmaxf(v.z, __shfl_xor(v.z, off, 64));
            v.w = fmaxf(v.w, __shfl_xor(v.w, off, 64));
        }
        if (l15 == 0) *(f32x4*)&maxbuf[wsi][wt + i2 * 16 + l4 * 4] = v;
    }
    __syncthreads();
    if (tid < 128) {
        float v = fmaxf(maxbuf[0][tid], maxbuf[1][tid]);
        out[((size_t)b * TT + t0 + tid) * NM + m] = tanhf(v);
    }
}

extern "C" void kernel_launch(void* const* d_in, const int* in_sizes, int n_in,
                              void* d_out, int out_size, void* d_ws, size_t ws_size,
                              hipStream_t stream) {
    const float* lt  = (const float*)d_in[0];   // (32,256,512) fp32
    const float* rt  = (const float*)d_in[1];   // (32,256,512) fp32
    const float* km  = (const float*)d_in[2];   // (20,512) fp32
    float*       out = (float*)d_out;           // (32,256,20) fp32

    const size_t elems = (size_t)NB * TT * DD;  // 4,194,304
    const size_t rtfB  = elems;                 // 4.19 MB fp8 (tiled)

    if (ws_size >= rtfB) {
        unsigned char* rtf = (unsigned char*)d_ws;
        cast_rt<<<512, 256, 0, stream>>>(rt, rtf);           // 32 elem/thread, XCD-aligned
        mp_match_mx<<<512, 256, 0, stream>>>(lt, rtf, km, out);  // 2 blocks/CU, G=5 m-loop
    } else {
        mp_match_kernel<<<dim3(2, NM, NB), 256, 0, stream>>>(lt, rt, km, out);
    }
}